// Round 12
// baseline (115.401 us; speedup 1.0000x reference)
//
#include <hip/hip_runtime.h>

// HeadlessAttention: B=2, K=512, Q=512, T=128
//
// logits[b,kk,q,u] = (Q_hat[b] @ diag(k[b,kk,:]) Wl^T)[q,u]
// swishmax over q (per b,kk,u); out = (sum_kk v[kk,u]*scale) @ Wo^T
//
// R12: REGISTER-PRESSURE A/B. Theory: R11 (2kk held: af64+C64+acc32+pf16
// +misc ~220 regs) silently spills acc/C -> scratch ld/st per iteration
// explains the 4-5x cycle inflation that made every schedule tweak
// (R7/R10/R11) neutral. This round: R9's shape (512thr, 8 waves, wave =
// 64q x 32u, 1 kk/iter, B-read feeds 2 MFMAs) but __launch_bounds__(512,2)
// (VGPR cap 256; R9's (512,4) capped at 128 and provably spilled:
// WRITE 38MB, K2 70us) and the proven single-barrier dbuf schedule.
// Estimated regs ~170: af 64 + C 32 + acc 32 + wl 8 + prefetch 8 + misc.
// No setprio (T5 null-to-negative in lockstep GEMM, m190).
// NOTE: ~42us of dur_us is the harness's 256MiB d_ws poison fill - fixed.

using f16    = _Float16;
using f16x8  = __attribute__((ext_vector_type(8)))  f16;
using f32x16 = __attribute__((ext_vector_type(16))) float;

#define LOG2E 1.4426950408889634f

__device__ __forceinline__ float exp2b(float x) {
  return __builtin_amdgcn_exp2f(x);
}

__device__ __forceinline__ f16x8 cvt8(float4 a, float4 b) {
  f16x8 r;
  r[0]=(f16)a.x; r[1]=(f16)a.y; r[2]=(f16)a.z; r[3]=(f16)a.w;
  r[4]=(f16)b.x; r[5]=(f16)b.y; r[6]=(f16)b.z; r[7]=(f16)b.w;
  return r;
}

// ---------------- K1: q,k,v projections ----------------
__global__ __launch_bounds__(256, 2) void k1_proj(
    const float* __restrict__ q_tok, const float* __restrict__ k_tok,
    const float* __restrict__ v_tok, const float* __restrict__ Wq,
    const float* __restrict__ Wk,    const float* __restrict__ Wv,
    f16* __restrict__ qh, float* __restrict__ kls, float* __restrict__ vf)
{
  const int gid    = blockIdx.x;        // 0..47
  const int tensor = gid >> 4;          // 0=q 1=k 2=v
  const int sub    = gid & 15;
  const int b      = sub >> 3;
  const int rt     = sub & 7;
  const float* X = tensor==0 ? q_tok : (tensor==1 ? k_tok : v_tok);
  const float* W = tensor==0 ? Wq    : (tensor==1 ? Wk    : Wv);

  const int tid = threadIdx.x;
  const int w = tid >> 6, lane = tid & 63;
  const int l31 = lane & 31, lhi = lane >> 5;
  const int rbase = rt*64 + (w>>1)*32;
  const int cbase = (w&1)*64;

  f32x16 C0, C1;
  #pragma unroll
  for (int i=0;i<16;++i){ C0[i]=0.f; C1[i]=0.f; }

  #pragma unroll
  for (int kc=0; kc<8; ++kc) {
    const float* ap = X + (size_t)(b*512 + rbase + l31)*128 + kc*16 + 8*lhi;
    f16x8 a = cvt8(*(const float4*)ap, *(const float4*)(ap+4));
    const float* bp0 = W + (size_t)(cbase + l31)*128 + kc*16 + 8*lhi;
    f16x8 b0 = cvt8(*(const float4*)bp0, *(const float4*)(bp0+4));
    C0 = __builtin_amdgcn_mfma_f32_32x32x16_f16(a, b0, C0, 0, 0, 0);
    const float* bp1 = bp0 + 32*128;
    f16x8 b1 = cvt8(*(const float4*)bp1, *(const float4*)(bp1+4));
    C1 = __builtin_amdgcn_mfma_f32_32x32x16_f16(a, b1, C1, 0, 0, 0);
  }

  #pragma unroll
  for (int us=0; us<2; ++us) {
    #pragma unroll
    for (int r=0; r<16; ++r) {
      const int row = rbase + (r&3) + 8*(r>>2) + 4*lhi;   // verified C/D layout
      const int col = cbase + us*32 + l31;
      const float val = us ? C1[r] : C0[r];
      const size_t idx = (size_t)(b*512 + row)*128 + col;
      if (tensor==0)      qh[idx]  = (f16)val;
      else if (tensor==1) kls[idx] = val * LOG2E;   // fold log2e into k
      else                vf[idx]  = val;
    }
  }
}

// ---------------- K2: fused logits + swishmax + v-scale --------------------
// grid 256 = b(2) x uq(4: 32 u) x grp(32: 16 kk). 512 thr = 8 waves,
// wave = 64 q (2x32 subtiles; each B-read feeds 2 MFMAs) x 32 u.
// 1 kk per iteration, ONE barrier per iteration, (512,2): VGPR cap 256,
// est. ~170 used -> no spill. Partials -> block-private 32KB region.
__global__ __launch_bounds__(512, 2) void k2_main(
    const f16* __restrict__ qh, const float* __restrict__ kls,
    const float* __restrict__ vf, const float* __restrict__ Wl,
    f16* __restrict__ part)
{
  const int gid  = blockIdx.x;          // 0..255
  const int b    = gid >> 7;
  const int uq   = (gid >> 5) & 3;
  const int grp  = gid & 31;
  const int kk0  = grp * 16;

  const int tid = threadIdx.x;
  const int w = tid >> 6, lane = tid & 63;
  const int l31 = lane & 31, lhi = lane >> 5;
  const int ubase = uq * 32;
  const int qbase = w * 64;

  __shared__ f16    Bl[2][32][136];     // [dbuf][u][t] scaled Wl, +8 pad
  __shared__ float2 red[2][8][32];      // (max, sum) per wave x u-col, dbuf

  // ---- A fragments: 64 q-rows (2 subtiles), register-resident (64 VGPR)
  f16x8 af[2][8];
  {
    const f16* ab = qh + (size_t)(b*512 + qbase + l31)*128 + 8*lhi;
    #pragma unroll
    for (int qs=0; qs<2; ++qs)
      #pragma unroll
      for (int kc=0; kc<8; ++kc)
        af[qs][kc] = *(const f16x8*)(ab + qs*32*128 + kc*16);
  }

  // ---- B-build mapping: 16 threads per u-row, 8 t each
  const int bu  = tid >> 4;    // 0..31 : local u
  const int btc = tid & 15;    // 0..15 : 8-wide t chunk
  const float* wlr = Wl + (size_t)(ubase + bu)*128 + btc*8;
  const float4 wl0 = *(const float4*)(wlr);
  const float4 wl1 = *(const float4*)(wlr+4);

  const float* kbase = kls + (size_t)(b*512 + kk0)*128 + btc*8;
  const float* vbase = vf  + (size_t)(b*512 + kk0)*128 + ubase;

  f32x16 acc[2];
  #pragma unroll
  for (int i=0;i<16;++i){ acc[0][i]=0.f; acc[1][i]=0.f; }

  // ---- prologue: build Bl[0] for kk0; prefetch k-slice kk0+1
  {
    const float4 k0 = *(const float4*)(kbase);
    const float4 k1 = *(const float4*)(kbase+4);
    float4 a0 = make_float4(wl0.x*k0.x, wl0.y*k0.y, wl0.z*k0.z, wl0.w*k0.w);
    float4 a1 = make_float4(wl1.x*k1.x, wl1.y*k1.y, wl1.z*k1.z, wl1.w*k1.w);
    *(f16x8*)(&Bl[0][bu][btc*8]) = cvt8(a0, a1);
  }
  float4 n0 = *(const float4*)(kbase + 128);
  float4 n1 = *(const float4*)(kbase + 132);
  __syncthreads();

  for (int i=0; i<16; ++i) {
    const int cur = i & 1;

    const float v0 = vbase[i*128 + l31];

    // build next B-tile (safe: Bl[cur^1] readers finished before the
    // previous iteration's barrier)
    if (i < 15) {
      float4 a0 = make_float4(wl0.x*n0.x, wl0.y*n0.y, wl0.z*n0.z, wl0.w*n0.w);
      float4 a1 = make_float4(wl1.x*n1.x, wl1.y*n1.y, wl1.z*n1.z, wl1.w*n1.w);
      *(f16x8*)(&Bl[cur^1][bu][btc*8]) = cvt8(a0, a1);
      if (i < 14) {
        const float* kp = kbase + (i+2)*128;
        n0 = *(const float4*)(kp);
        n1 = *(const float4*)(kp+4);
      }
    }

    // MFMA: each B-read feeds TWO MFMAs (q-subtiles 0/1)
    f32x16 C0, C1;
    #pragma unroll
    for (int j=0;j<16;++j){ C0[j]=0.f; C1[j]=0.f; }
    #pragma unroll
    for (int kc=0; kc<8; ++kc) {
      f16x8 bfr = *(const f16x8*)(&Bl[cur][l31][kc*16 + 8*lhi]);
      C0 = __builtin_amdgcn_mfma_f32_32x32x16_f16(af[0][kc], bfr, C0, 0,0,0);
      C1 = __builtin_amdgcn_mfma_f32_32x32x16_f16(af[1][kc], bfr, C1, 0,0,0);
    }

    // single pass: p = y*2^y, track max(y), sum|p|
    float mxa=-3.4e38f, mxb=-3.4e38f, sa=0.f, sb=0.f;
    #pragma unroll
    for (int r=0; r<16; ++r) {
      const float y0 = C0[r], y1 = C1[r];
      const float p0 = y0 * exp2b(y0);
      const float p1 = y1 * exp2b(y1);
      C0[r] = p0; C1[r] = p1;
      if (r & 1) { mxb=fmaxf(mxb,fmaxf(y0,y1)); sb+=fabsf(p0)+fabsf(p1); }
      else       { mxa=fmaxf(mxa,fmaxf(y0,y1)); sa+=fabsf(p0)+fabsf(p1); }
    }
    float mx = fmaxf(mxa, mxb);
    float sm = sa + sb;
    mx = fmaxf(mx, __shfl_xor(mx, 32));
    sm += __shfl_xor(sm, 32);
    if (lane < 32) red[cur][w][lane] = make_float2(mx, sm);

    __syncthreads();   // the ONLY barrier: red[cur] ready; Bl[cur^1] built

    // hierarchical cross-wave reduce: half-wave reads 4 entries, then
    // shfl_xor(32) merges the two halves
    float M = -3.4e38f, S = 0.f;
    #pragma unroll
    for (int j=0; j<4; ++j) {
      const float2 t = red[cur][4*lhi + j][l31];
      M = fmaxf(M, t.x); S += t.y;
    }
    M = fmaxf(M, __shfl_xor(M, 32));
    S += __shfl_xor(S, 32);

    const float su = v0 / (S + LOG2E * exp2b(M));

    #pragma unroll
    for (int r=0; r<16; ++r) {
      acc[0][r] = fmaf(su, C0[r], acc[0][r]);
      acc[1][r] = fmaf(su, C1[r], acc[1][r]);
    }
  }

  // ---- block-private contiguous partial store: part[s][q 512][ul 32] f16
  {
    const int s = (grp<<3) + (b<<2) + uq;
    f16* pbase = part + (size_t)s*16384 + l31;
    #pragma unroll
    for (int qs=0; qs<2; ++qs)
      #pragma unroll
      for (int r=0; r<16; ++r) {
        const int q = qbase + qs*32 + (r&3) + 8*(r>>2) + 4*lhi;
        pbase[q*32] = (f16)acc[qs][r];
      }
  }
}

// ---------------- K3: reduce 32 slab-groups + out = vsum @ Wo^T (fused) ----
// grid 32 = qt(16, 32 q-rows) x b(2). 256 thr = 4 waves.
__global__ __launch_bounds__(256, 2) void k3_out(
    const f16* __restrict__ part, const float* __restrict__ Wo,
    float* __restrict__ out)
{
  const int gid = blockIdx.x;     // 0..31
  const int qt = gid >> 1, b = gid & 1;
  const int rbase = qt * 32;
  const int tid = threadIdx.x;

  __shared__ f16 vt[32][136];     // reduced vsum tile, f16

  // phase 1: slab reduction. thread -> (q = tid>>3, uc = tid&7: 16-u chunk)
  {
    const int q  = tid >> 3;
    const int uc = tid & 7;
    const int uq  = uc >> 1;            // 32-u quarter -> slab sub-index
    const int ul0 = (uc & 1) * 16;      // offset within the 32-u slab row

    float s[16];
    #pragma unroll
    for (int j=0;j<16;++j) s[j]=0.f;

    const f16* pb = part + (size_t)((b<<2) + uq)*16384 + (rbase + q)*32 + ul0;
    for (int g=0; g<32; ++g) {
      const f16x8 p0 = *(const f16x8*)(pb + (size_t)g*131072);
      const f16x8 p1 = *(const f16x8*)(pb + (size_t)g*131072 + 8);
      #pragma unroll
      for (int j=0;j<8;++j) { s[j] += (float)p0[j]; s[8+j] += (float)p1[j]; }
    }
    f16x8 o0, o1;
    #pragma unroll
    for (int j=0;j<8;++j) { o0[j] = (f16)s[j]; o1[j] = (f16)s[8+j]; }
    *(f16x8*)(&vt[q][uc*16])     = o0;
    *(f16x8*)(&vt[q][uc*16 + 8]) = o1;
  }
  __syncthreads();

  // phase 2: GEMM out[rbase..+32, :] = vt @ Wo^T ; wave w -> cols w*32..+32
  const int w = tid >> 6, lane = tid & 63;
  const int l31 = lane & 31, lhi = lane >> 5;
  const int cbase = w * 32;

  f32x16 C;
  #pragma unroll
  for (int i=0;i<16;++i) C[i] = 0.f;

  #pragma unroll
  for (int kc=0; kc<8; ++kc) {
    f16x8 a = *(const f16x8*)(&vt[l31][kc*16 + 8*lhi]);
    const float* bp = Wo + (size_t)(cbase + l31)*128 + kc*16 + 8*lhi;
    f16x8 bfr = cvt8(*(const float4*)bp, *(const float4*)(bp+4));
    C = __builtin_amdgcn_mfma_f32_32x32x16_f16(a, bfr, C, 0, 0, 0);
  }

  #pragma unroll
  for (int r=0; r<16; ++r) {
    const int row = rbase + (r&3) + 8*(r>>2) + 4*lhi;
    const int col = cbase + l31;
    out[(size_t)(b*512 + row)*128 + col] = C[r];
  }
}

extern "C" void kernel_launch(void* const* d_in, const int* in_sizes, int n_in,
                              void* d_out, int out_size, void* d_ws, size_t ws_size,
                              hipStream_t stream) {
  const float* q_tok = (const float*)d_in[0];
  const float* k_tok = (const float*)d_in[1];
  const float* v_tok = (const float*)d_in[2];
  const float* Wk    = (const float*)d_in[3];
  const float* Wq    = (const float*)d_in[4];
  const float* Wv    = (const float*)d_in[5];
  const float* Wl    = (const float*)d_in[6];
  const float* Wo    = (const float*)d_in[7];

  char* ws = (char*)d_ws;
  f16*   qh   = (f16*)  (ws);              // 262144 B
  float* kls  = (float*)(ws + 262144);     // 524288 B
  float* vf   = (float*)(ws + 786432);     // 524288 B
  f16*   part = (f16*)  (ws + 1310720);    // 256 slabs * 32KB = 8388608 B

  k1_proj<<<48, 256, 0, stream>>>(q_tok, k_tok, v_tok, Wq, Wk, Wv, qh, kls, vf);
  k2_main<<<256, 512, 0, stream>>>(qh, kls, vf, Wl, part);
  k3_out<<<32, 256, 0, stream>>>(part, Wo, (float*)d_out);
}